// Round 4
// baseline (788.049 us; speedup 1.0000x reference)
//
#include <hip/hip_runtime.h>

// LSTMDecoder: B=4096, LATENT=128, SEQ=512, HID=32, OUT=64. f32 in/out.
// Round 12: WAVE-LOCAL recurrence — zero LDS, zero barriers, zero cross-lane.
//
//  - One wave (64 threads) owns a full 16-row batch tile. Gate output tiles
//    (s,G), s=0..1, G=0..3 (i,f,g,o), built from W_hh rows [32G+16s ..
//    32G+16s+16) in IDENTITY order. Then D-layout gives lane (n,q) reg r =
//    gate G of cell 16s+4q+r — and the B-frag slots of lane (n,q) are exactly
//    cells {4q+r} (slots 0-3) and {16+4q+r} (slots 4-7). Producer == consumer
//    lane: the recurrence closes entirely in-lane. No exchange.
//  - Per step: 8 gate MFMAs + activation of 8 cells/lane (80 transcendentals,
//    8 independent chains, pipelined) + in-lane f16 repack + 4 proj MFMAs +
//    4 global_store_dwordx4 (fire-and-forget, vmcnt never waited).
//  - Scale folding kept from r10/r11: -log2e into i,f,o tiles; +2log2e into g
//    tile; cell state kept pre-scaled by 2log2e (cs = 2log2e*c).
//  - h0 computed per-lane for its 8 owned cells (z row L1-hot across cells).
//  - Grid: 256 blocks x 64 threads (1 wave/CU), fully independent waves.

#define B_SZ   4096
#define LATENT 128
#define SEQ    512
#define HID    32
#define OUT_N  64
#define ROWS   16

typedef _Float16 f16x8 __attribute__((ext_vector_type(8)));
typedef float    f32x4 __attribute__((ext_vector_type(4)));

__device__ __forceinline__ float fexp2(float x) { return __builtin_amdgcn_exp2f(x); }
__device__ __forceinline__ float frcp(float x)  { return __builtin_amdgcn_rcpf(x); }

__global__ __launch_bounds__(64)
void lstm_wl12(const float* __restrict__ z,
               const float* __restrict__ init_W,
               const float* __restrict__ init_b,
               const float* __restrict__ W_hh,
               const float* __restrict__ b_ih,
               const float* __restrict__ b_hh,
               const float* __restrict__ out_W,
               const float* __restrict__ out_b,
               float* __restrict__ y)
{
    const int lane = threadIdx.x;       // 0..63
    const int n_   = lane & 15;         // batch row within tile (MFMA col)
    const int q    = lane >> 4;         // quad index (MFMA row group)
    const int rbase = blockIdx.x * ROWS;

    const float NL2E  = -1.44269504088896341f;   // -log2(e)
    const float P2L2E =  2.88539008177792681f;   // +2*log2(e)

    // ---- gate A-frags: tile t=4s+G from W_hh rows 32G+16s+m (identity) ----
    f16x8 wf[8];
    f32x4 bacc[8];
#pragma unroll
    for (int s = 0; s < 2; s++) {
#pragma unroll
        for (int G = 0; G < 4; G++) {
            const int t = 4 * s + G;
            const float sc = (G == 2) ? P2L2E : NL2E;
            const float* row = W_hh + (size_t)(32 * G + 16 * s + n_) * HID;
            f16x8 v;
#pragma unroll
            for (int rr = 0; rr < 4; rr++) {
                v[rr]     = (_Float16)(sc * row[4 * q + rr]);
                v[4 + rr] = (_Float16)(sc * row[16 + 4 * q + rr]);
            }
            wf[t] = v;
            f32x4 b;
#pragma unroll
            for (int r = 0; r < 4; r++) {
                const int gr = 32 * G + 16 * s + 4 * q + r;
                b[r] = sc * (b_ih[gr] + b_hh[gr]);
            }
            bacc[t] = b;
        }
    }

    // ---- proj A-frags: tile p from out_W rows 16p+m ----
    f16x8 owf[4];
    f32x4 oacc[4];
#pragma unroll
    for (int p = 0; p < 4; p++) {
        const float* row = out_W + (size_t)(16 * p + n_) * HID;
        f16x8 v;
#pragma unroll
        for (int rr = 0; rr < 4; rr++) {
            v[rr]     = (_Float16)row[4 * q + rr];
            v[4 + rr] = (_Float16)row[16 + 4 * q + rr];
        }
        owf[p] = v;
#pragma unroll
        for (int r = 0; r < 4; r++) oacc[p][r] = out_b[16 * p + 4 * q + r];
    }

    // ---- h0 for this lane's 8 owned cells: c = 16s + 4q + r ----
    f16x8 a;
    float cs[8];
    {
        const float4* zp = (const float4*)(z + (size_t)(rbase + n_) * LATENT);
#pragma unroll
        for (int s = 0; s < 2; s++) {
#pragma unroll
            for (int r = 0; r < 4; r++) {
                const int c = 16 * s + 4 * q + r;
                const float4* wp = (const float4*)(init_W + (size_t)c * LATENT);
                float acc0 = init_b[c];
#pragma unroll 8
                for (int k = 0; k < LATENT / 4; k++) {
                    float4 a4 = zp[k], b4 = wp[k];
                    acc0 = fmaf(a4.x, b4.x, acc0); acc0 = fmaf(a4.y, b4.y, acc0);
                    acc0 = fmaf(a4.z, b4.z, acc0); acc0 = fmaf(a4.w, b4.w, acc0);
                }
                a[4 * s + r] = (_Float16)acc0;
                cs[4 * s + r] = 0.f;
            }
        }
    }

    float* yb = y + (size_t)(rbase + n_) * SEQ * OUT_N + 4 * q;

    for (int it = 0; it < SEQ; it++) {
        // ---- 8 gate MFMAs (B = a shared, all independent) ----
        f32x4 acc[8];
#pragma unroll
        for (int t = 0; t < 8; t++)
            acc[t] = __builtin_amdgcn_mfma_f32_16x16x32_f16(wf[t], a, bacc[t], 0, 0, 0);

        // ---- activation: 8 cells/lane, independent chains; rewrite a in-lane ----
#pragma unroll
        for (int s = 0; s < 2; s++) {
#pragma unroll
            for (int r = 0; r < 4; r++) {
                const int i8 = 4 * s + r;
                float gi = frcp(1.f + fexp2(acc[4 * s + 0][r]));
                float gf = frcp(1.f + fexp2(acc[4 * s + 1][r]));
                float rg = frcp(1.f + fexp2(acc[4 * s + 2][r]));
                float go = frcp(1.f + fexp2(acc[4 * s + 3][r]));
                float g2 = fmaf(-2.f * P2L2E, rg, P2L2E);   // 2log2e * tanh(pre_g)
                float csn = fmaf(gf, cs[i8], gi * g2);
                cs[i8] = csn;
                float rt = frcp(1.f + fexp2(csn));
                a[i8] = (_Float16)fmaf(-2.f * go, rt, go);  // go * tanh(c)
            }
        }

        // ---- projection of h_{it+1} -> y[it]; stores are fire-and-forget ----
#pragma unroll
        for (int p = 0; p < 4; p++) {
            f32x4 py = __builtin_amdgcn_mfma_f32_16x16x32_f16(owf[p], a, oacc[p], 0, 0, 0);
            *(f32x4*)(yb + (size_t)it * OUT_N + 16 * p) = py;
        }
    }
}

extern "C" void kernel_launch(void* const* d_in, const int* in_sizes, int n_in,
                              void* d_out, int out_size, void* d_ws, size_t ws_size,
                              hipStream_t stream) {
    const float* z      = (const float*)d_in[0];
    const float* init_W = (const float*)d_in[1];
    const float* init_b = (const float*)d_in[2];
    // d_in[3] = W_ih: unused (x input is all zeros; only biases survive)
    const float* W_hh   = (const float*)d_in[4];
    const float* b_ih   = (const float*)d_in[5];
    const float* b_hh   = (const float*)d_in[6];
    const float* out_W  = (const float*)d_in[7];
    const float* out_b  = (const float*)d_in[8];
    float* yout = (float*)d_out;

    lstm_wl12<<<B_SZ / ROWS, 64, 0, stream>>>(z, init_W, init_b, W_hh, b_ih, b_hh,
                                              out_W, out_b, yout);
}

// Round 5
// 603.101 us; speedup vs baseline: 1.3067x; 1.3067x over previous
//
#include <hip/hip_runtime.h>

// LSTMDecoder: B=4096, LATENT=128, SEQ=512, HID=32, OUT=64. f32 in/out.
// Round 13: WAVE SPECIALIZATION — 4 recurrence waves + 4 projection waves.
//
//  - Model (fits r11=1140 cyc/step AND r12=2050): transc issue ~16 cyc/wave64;
//    per-CU transc work invariant (512 cells x 10). Winning structure keeps
//    transc spread over 4 SIMDs and strips everything else off the rec chain.
//  - Waves 0-3 (rec): wave w -> s=w>>1, p0=w&1; owns cells 16s+4q+2p0+{0,1}
//    per lane (n,q). Two fused-gate MFMAs (row-permuted Atil_m: row d :=
//    W_hh row 32*(d&3)+16s+4*(d>>2)+2p0+m) give reg r = gate r of cell m.
//    Act for 2 cells (20 transc, 2 indep chains), pack 2 f16 -> ONE b32 LDS
//    write at slot 4s+2p0 (2-way bank, free). Producer lane == consumer lane:
//    rebuild = 4x conflict-free b32 from own hx row (as r11).
//  - Waves 4-7 (proj): after the barrier, rebuild h, 1 proj MFMA (tile p=w-4),
//    1 global_store_dwordx4 -> y[n][t][16p+4q..+3]. No transc, no hx writes;
//    parks early at barrier. SIMD k hosts rec wave k + proj wave k+4: proj
//    issue fills rec stall shadows.
//  - One lgkm-only barrier per step, parity double-buffered hx (r11 proven).
//  - Scale folding kept: -log2e (i,f,o) / +2log2e (g); cs pre-scaled 2log2e.

#define B_SZ   4096
#define LATENT 128
#define SEQ    512
#define HID    32
#define OUT_N  64
#define ROWS   16
#define LSW    40   // h0 staging row stride in halves (80 B rows)
#define HXW    10   // hx row stride in halves (20 B rows, 2-way banks = free)

typedef _Float16 f16x8 __attribute__((ext_vector_type(8)));
typedef _Float16 f16x4 __attribute__((ext_vector_type(4)));
typedef float    f32x4 __attribute__((ext_vector_type(4)));

__device__ __forceinline__ float fexp2(float x) { return __builtin_amdgcn_exp2f(x); }
__device__ __forceinline__ float frcp(float x)  { return __builtin_amdgcn_rcpf(x); }
__device__ __forceinline__ void lds_barrier() {
    asm volatile("s_waitcnt lgkmcnt(0)\n\ts_barrier" ::: "memory");
}

__global__ __launch_bounds__(512)
void lstm_ws13(const float* __restrict__ z,
               const float* __restrict__ init_W,
               const float* __restrict__ init_b,
               const float* __restrict__ W_hh,
               const float* __restrict__ b_ih,
               const float* __restrict__ b_hh,
               const float* __restrict__ out_W,
               const float* __restrict__ out_b,
               float* __restrict__ y)
{
    __shared__ __align__(16) _Float16 hst[ROWS * LSW];
    __shared__ __align__(4) unsigned short hx[2][64][HXW];

    const int tid  = threadIdx.x;
    const int w    = tid >> 6;          // wave 0..7
    const int lane = tid & 63;
    const int n_   = lane & 15;         // batch row within tile (MFMA col)
    const int q    = lane >> 4;         // quad group (MFMA row group)
    const int rbase = blockIdx.x * ROWS;
    const bool isrec = (w < 4);

    const float NL2E  = -1.44269504088896341f;   // -log2(e)
    const float P2L2E =  2.88539008177792681f;   // +2*log2(e)

    // ---- rec waves: two fused-gate A-frags + biases ----
    const int s_  = (w >> 1) & 1;       // cell half (rec)
    const int p0  = w & 1;              // cell pair within quad (rec)
    f16x8 wf0, wf1;
    f32x4 bacc0, bacc1;
    if (isrec) {
#pragma unroll
        for (int m = 0; m < 2; m++) {
            // Atil_m row n_ = W_hh row 32*(n_&3) + 16s + 4*(n_>>2) + 2p0 + m
            const int arow = 32 * (n_ & 3) + 16 * s_ + 4 * (n_ >> 2) + 2 * p0 + m;
            const float asc = ((n_ & 3) == 2) ? P2L2E : NL2E;
            const float* wrow = W_hh + (size_t)arow * HID;
            f16x8 v;
#pragma unroll
            for (int rr = 0; rr < 4; rr++) {
                v[rr]     = (_Float16)(asc * wrow[4 * q + rr]);
                v[4 + rr] = (_Float16)(asc * wrow[16 + 4 * q + rr]);
            }
            f32x4 b;
#pragma unroll
            for (int r = 0; r < 4; r++) {
                const int G = 32 * r + 16 * s_ + 4 * q + 2 * p0 + m;
                const float bsc = (r == 2) ? P2L2E : NL2E;
                b[r] = bsc * (b_ih[G] + b_hh[G]);
            }
            if (m == 0) { wf0 = v; bacc0 = b; } else { wf1 = v; bacc1 = b; }
        }
    }

    // ---- proj waves: A-frag tile p = w-4 ----
    f16x8 owf;
    f32x4 oacc;
    if (!isrec) {
        const int p = w - 4;
        const float* row = out_W + (size_t)(16 * p + n_) * HID;
#pragma unroll
        for (int rr = 0; rr < 4; rr++) {
            owf[rr]     = (_Float16)row[4 * q + rr];
            owf[4 + rr] = (_Float16)row[16 + 4 * q + rr];
        }
#pragma unroll
        for (int r = 0; r < 4; r++) oacc[r] = out_b[16 * p + 4 * q + r];
    }

    // ---- h0 = z @ init_W^T + init_b (one cell per thread: 512 = 16x32) ----
    {
        int m = tid >> 5, j = tid & 31;
        const float4* zp = (const float4*)(z + (size_t)(rbase + m) * LATENT);
        const float4* wp = (const float4*)(init_W + (size_t)j * LATENT);
        float acc = init_b[j];
#pragma unroll
        for (int k = 0; k < LATENT / 4; k++) {
            float4 a4 = zp[k], b4 = wp[k];
            acc = fmaf(a4.x, b4.x, acc); acc = fmaf(a4.y, b4.y, acc);
            acc = fmaf(a4.z, b4.z, acc); acc = fmaf(a4.w, b4.w, acc);
        }
        hst[m * LSW + j] = (_Float16)acc;
    }
    __syncthreads();

    // initial fragment (rec only): slot 4s'+rr <- h0[n_][4q+rr / 16+4q+rr]
    f16x8 a;
    if (isrec) {
        f16x4 lo = *(const f16x4*)&hst[n_ * LSW + 4 * q];
        f16x4 hi = *(const f16x4*)&hst[n_ * LSW + 4 * q + 16];
#pragma unroll
        for (int r = 0; r < 4; r++) { a[r] = lo[r]; a[4 + r] = hi[r]; }
    }

    float cs0 = 0.f, cs1 = 0.f;   // 2log2e-scaled cell states (rec)

    float* yb = y + (size_t)(rbase + n_) * SEQ * OUT_N + 16 * (w - 4) + 4 * q;

    for (int t = 0; t < SEQ; t += 4) {
#pragma unroll
        for (int u = 0; u < 4; u++) {
            const int par = u & 1;
            if (isrec) {
                // ---- gates: 2 fused MFMAs (reg r = gate r of cell m) ----
                f32x4 ac0 = __builtin_amdgcn_mfma_f32_16x16x32_f16(wf0, a, bacc0, 0, 0, 0);
                f32x4 ac1 = __builtin_amdgcn_mfma_f32_16x16x32_f16(wf1, a, bacc1, 0, 0, 0);

                // ---- act cell m=0 ----
                float gi0 = frcp(1.f + fexp2(ac0[0]));
                float gf0 = frcp(1.f + fexp2(ac0[1]));
                float rg0 = frcp(1.f + fexp2(ac0[2]));
                float go0 = frcp(1.f + fexp2(ac0[3]));
                float g20 = fmaf(-2.f * P2L2E, rg0, P2L2E);
                float cn0 = fmaf(gf0, cs0, gi0 * g20);
                cs0 = cn0;
                float rt0 = frcp(1.f + fexp2(cn0));
                float h0v = fmaf(-2.f * go0, rt0, go0);
                // ---- act cell m=1 ----
                float gi1 = frcp(1.f + fexp2(ac1[0]));
                float gf1 = frcp(1.f + fexp2(ac1[1]));
                float rg1 = frcp(1.f + fexp2(ac1[2]));
                float go1 = frcp(1.f + fexp2(ac1[3]));
                float g21 = fmaf(-2.f * P2L2E, rg1, P2L2E);
                float cn1 = fmaf(gf1, cs1, gi1 * g21);
                cs1 = cn1;
                float rt1 = frcp(1.f + fexp2(cn1));
                float h1v = fmaf(-2.f * go1, rt1, go1);

                // ---- pack both halves, ONE b32 write at slot 4s+2p0 ----
                union { _Float16 h[2]; unsigned u32; } cv;
                cv.h[0] = (_Float16)h0v;
                cv.h[1] = (_Float16)h1v;
                *(unsigned*)&hx[par][lane][4 * s_ + 2 * p0] = cv.u32;

                lds_barrier();

                // ---- rebuild fragment: 4x b32 from OWN row, slot order ----
                union { unsigned u[4]; f16x8 v; } ua;
                const unsigned* rp = (const unsigned*)&hx[par][lane][0];
                ua.u[0] = rp[0]; ua.u[1] = rp[1]; ua.u[2] = rp[2]; ua.u[3] = rp[3];
                a = ua.v;
            } else {
                lds_barrier();

                // ---- rebuild h_{t+1}, project, store y[t] ----
                union { unsigned u[4]; f16x8 v; } ua;
                const unsigned* rp = (const unsigned*)&hx[par][lane][0];
                ua.u[0] = rp[0]; ua.u[1] = rp[1]; ua.u[2] = rp[2]; ua.u[3] = rp[3];
                a = ua.v;
                f32x4 py = __builtin_amdgcn_mfma_f32_16x16x32_f16(owf, a, oacc, 0, 0, 0);
                *(f32x4*)(yb + (size_t)(t + u) * OUT_N) = py;
            }
        }
    }
}

extern "C" void kernel_launch(void* const* d_in, const int* in_sizes, int n_in,
                              void* d_out, int out_size, void* d_ws, size_t ws_size,
                              hipStream_t stream) {
    const float* z      = (const float*)d_in[0];
    const float* init_W = (const float*)d_in[1];
    const float* init_b = (const float*)d_in[2];
    // d_in[3] = W_ih: unused (x input is all zeros; only biases survive)
    const float* W_hh   = (const float*)d_in[4];
    const float* b_ih   = (const float*)d_in[5];
    const float* b_hh   = (const float*)d_in[6];
    const float* out_W  = (const float*)d_in[7];
    const float* out_b  = (const float*)d_in[8];
    float* yout = (float*)d_out;

    lstm_ws13<<<B_SZ / ROWS, 512, 0, stream>>>(z, init_W, init_b, W_hh, b_ih, b_hh,
                                               out_W, out_b, yout);
}